// Round 12
// baseline (79.070 us; speedup 1.0000x reference)
//
#include <hip/hip_runtime.h>

#define BB 32
#define NN 512
#define PP 128
#define MM (BB * NN)  // 16384 rows

typedef unsigned int u32;
typedef unsigned short u16;

typedef __attribute__((ext_vector_type(8))) short short8v;  // 8 bf16 (4 VGPR)
typedef __attribute__((ext_vector_type(4))) float f32x4;

// ---- ws layout ----
#define POSP_OFF 0                      // [8][MM] f32
#define NEGP_OFF (8 * MM)               // [8][MM] f32
#define UVB_OFF (16 * MM)               // u[128], v[128], bias[128]
#define PFIN_OFF (16 * MM + 512)        // pos final [MM]
#define NFIN_OFF (16 * MM + 512 + MM)   // neg final [MM]
// byte offsets (ws ~268 MB per 0xAA-fill evidence)
#define ADJB_OFF ((size_t)4194304)       // u16 [BB][NN][NN] = 16 MB
#define MUHI_OFF ((size_t)20971520)      // u16 [BB][NN][PP] = 4 MB (row-major)
#define MULO_OFF ((size_t)25165824)      // u16 [BB][NN][PP] = 4 MB
#define W2T_OFF ((size_t)29360128)       // u16 [PP][PP] = 32 KB (W2T[p][q]=bf16(W2[q][p]))
#define MW2HI_OFF ((size_t)29392896)     // u16 [BB][PP][NN] = 4 MB (muW2T hi)
#define MW2LO_OFF ((size_t)33587200)     // u16 [BB][PP][NN] = 4 MB (muW2T lo)

__device__ inline u32 bf16rne(float f) {
    u32 u = __float_as_uint(f);
    return (u + 0x7FFFu + ((u >> 16) & 1u)) >> 16;
}

// prep (r10/r11 verbatim): pos/neg partials + adj as bf16.
__global__ __launch_bounds__(512) void k_prep(const float* __restrict__ weight,
                                              const float* __restrict__ adj,
                                              float* __restrict__ posP,
                                              float* __restrict__ negP,
                                              u16* __restrict__ adjb) {
    __shared__ float sps[8][128], sng[8][128];

    int b = blockIdx.z, seg = blockIdx.y;
    int tx = threadIdx.x;
    int jl2 = tx & 63;
    int g = tx >> 6;
    int j0tile = blockIdx.x * 128;
    int j = j0tile + jl2 * 2;

    size_t base = (size_t)b * NN * NN + ((size_t)seg * 64 + g * 8) * NN + j;
    const float2* wp = (const float2*)(weight + base);
    const float2* ap = (const float2*)(adj + base);
    u32* ab32 = (u32*)adjb + (base >> 1);
    float psx = 0.f, psy = 0.f, ngx = 0.f, ngy = 0.f;
#pragma unroll
    for (int k = 0; k < 8; ++k) {
        float2 a = ap[(size_t)k * (NN / 2)];
        float2 w = wp[(size_t)k * (NN / 2)];
        float wa0 = w.x * a.x;
        float wa1 = w.y * a.y;
        psx += fmaxf(wa0, 0.f);
        ngx += fmaxf(-wa0, 0.f);
        psy += fmaxf(wa1, 0.f);
        ngy += fmaxf(-wa1, 0.f);
        ab32[(size_t)k * (NN / 2)] =
            (a.x != 0.f ? 0x3F80u : 0u) | (a.y != 0.f ? 0x3F800000u : 0u);
    }
    sps[g][2 * jl2] = psx;
    sps[g][2 * jl2 + 1] = psy;
    sng[g][2 * jl2] = ngx;
    sng[g][2 * jl2 + 1] = ngy;
    __syncthreads();
    if (tx < 128) {
        float P = 0.f, Ng = 0.f;
#pragma unroll
        for (int g2 = 0; g2 < 8; ++g2) {
            P += sps[g2][tx];
            Ng += sng[g2][tx];
        }
        int row = b * NN + j0tile + tx;
        posP[seg * MM + row] = P;
        negP[seg * MM + row] = Ng;
    }
}

// aux (r11 verbatim): bid<64: mu -> hi/lo bf16 row-major; 64..71: pos/neg
// reduce; 72: uv+bias; 73: W2T bf16.
__global__ __launch_bounds__(256) void k_aux(
    const float* __restrict__ mu, const float* __restrict__ W2,
    const float* __restrict__ t4, const float* __restrict__ W3,
    const float* __restrict__ b1, const float* __restrict__ b2,
    const float* __restrict__ b3, const float* __restrict__ posP,
    const float* __restrict__ negP, float* __restrict__ posf,
    float* __restrict__ negf, float* __restrict__ uvb,
    u16* __restrict__ muhi, u16* __restrict__ mulo, u16* __restrict__ w2t) {
    __shared__ float su[2][PP], sv[2][PP];
    int bid = blockIdx.x;
    int t = threadIdx.x;
    if (bid < 64) {
        int gtid = bid * 256 + t;
        const float2* mu2 = (const float2*)mu;
        u32* hi32 = (u32*)muhi;
        u32* lo32 = (u32*)mulo;
#pragma unroll 8
        for (int s = 0; s < 64; ++s) {
            size_t idx = (size_t)s * 16384 + gtid;
            float2 v = mu2[idx];
            u32 h0 = bf16rne(v.x), h1 = bf16rne(v.y);
            float l0 = v.x - __uint_as_float(h0 << 16);
            float l1 = v.y - __uint_as_float(h1 << 16);
            hi32[idx] = h0 | (h1 << 16);
            lo32[idx] = bf16rne(l0) | (bf16rne(l1) << 16);
        }
    } else if (bid < 72) {
        int base = (bid - 64) * 2048;
#pragma unroll
        for (int rr = 0; rr < 8; ++rr) {
            int row = base + rr * 256 + t;
            float P = 0.f, Ng = 0.f;
#pragma unroll
            for (int s = 0; s < 8; ++s) {
                P += posP[s * MM + row];
                Ng += negP[s * MM + row];
            }
            posf[row] = P;
            negf[row] = Ng;
        }
    } else if (bid == 72) {
        int p = t & 127, h = t >> 7;
        float u = 0.f, v = 0.f;
#pragma unroll 8
        for (int q = h * 64; q < h * 64 + 64; ++q) {
            float tt = t4[q];
            float w = W3[q * PP + p];
            u += fmaxf(tt, 0.f) * w;
            v += fmaxf(-tt, 0.f) * w;
        }
        su[h][p] = u;
        sv[h][p] = v;
        __syncthreads();
        if (t < PP) {
            uvb[p] = su[0][p] + su[1][p];
            uvb[PP + p] = sv[0][p] + sv[1][p];
            uvb[2 * PP + p] = b1[p] + b2[p] + b3[p];
        }
    } else {
#pragma unroll 4
        for (int c = 0; c < 64; ++c) {
            int n = c * 256 + t;
            int q = n >> 7, pp = n & 127;
            w2t[pp * PP + q] = (u16)bf16rne(W2[q * PP + pp]);
        }
    }
}

// muw2 (r11 verbatim): muW2T[p][i] = sum_q W2T[p][q] * mu[i][q] (hi+lo).
__global__ __launch_bounds__(256) void k_muw2(
    const u16* __restrict__ w2t, const u16* __restrict__ muhi,
    const u16* __restrict__ mulo, u16* __restrict__ mw2hi,
    u16* __restrict__ mw2lo) {
    __shared__ __align__(16) u16 w2L[PP * 128];  // 32 KB, XOR-swizzled cols

    int bid = blockIdx.x;
    int vbid = ((bid & 7) << 5) | (bid >> 3);  // XCD chunking
    int b = vbid >> 3;
    int i0 = (vbid & 7) * 64;
    int tx = threadIdx.x, lane = tx & 63, w = tx >> 6;

    {
        int p = tx >> 1, qc = (tx & 1) * 64;
        const uint4* src = (const uint4*)(w2t + p * PP + qc);
#pragma unroll
        for (int c = 0; c < 8; ++c) {
            int q8 = (qc + c * 8) ^ ((p & 7) << 3);
            *(uint4*)&w2L[p * 128 + q8] = src[c];
        }
    }
    __syncthreads();

    const u16* mhB = muhi + (size_t)b * NN * PP;
    const u16* mlB = mulo + (size_t)b * NN * PP;

    f32x4 acc[2][4];  // [pt][it]
#pragma unroll
    for (int a = 0; a < 2; ++a)
#pragma unroll
        for (int c = 0; c < 4; ++c) acc[a][c] = (f32x4){0.f, 0.f, 0.f, 0.f};

#pragma unroll
    for (int ks = 0; ks < 4; ++ks) {
        int kb = ks * 32 + (lane >> 4) * 8;
        short8v afr[2];
#pragma unroll
        for (int pt = 0; pt < 2; ++pt) {
            int prow = w * 32 + pt * 16 + (lane & 15);
            afr[pt] = *(const short8v*)&w2L[prow * 128 + (kb ^ ((prow & 7) << 3))];
        }
#pragma unroll
        for (int it = 0; it < 4; ++it) {
            int irow = i0 + it * 16 + (lane & 15);
            short8v bh = *(const short8v*)&mhB[(size_t)irow * PP + kb];
            short8v bl = *(const short8v*)&mlB[(size_t)irow * PP + kb];
#pragma unroll
            for (int pt = 0; pt < 2; ++pt) {
                acc[pt][it] = __builtin_amdgcn_mfma_f32_16x16x32_bf16(afr[pt], bh, acc[pt][it], 0, 0, 0);
                acc[pt][it] = __builtin_amdgcn_mfma_f32_16x16x32_bf16(afr[pt], bl, acc[pt][it], 0, 0, 0);
            }
        }
    }

#pragma unroll
    for (int pt = 0; pt < 2; ++pt)
#pragma unroll
        for (int it = 0; it < 4; ++it)
#pragma unroll
            for (int r = 0; r < 4; ++r) {
                int p = w * 32 + pt * 16 + (lane >> 4) * 4 + r;
                int i = i0 + it * 16 + (lane & 15);
                float v = acc[pt][it][r];
                u32 h = bf16rne(v);
                float lf = v - __uint_as_float(h << 16);
                size_t off = ((size_t)b * PP + p) * NN + i;
                mw2hi[off] = (u16)h;
                mw2lo[off] = (u16)bf16rne(lf);
            }
}

// fused: out = relu(adj @ muW2T(hi+lo) + x*W1 + pos*u + neg*v + bias).
// r10's PROVEN geometry: 256 blocks = 32 b x 8 j-tiles(64); 256 thr = 4 waves,
// wave w owns p-slice [32w, 32w+32). Phase 2 deleted (associativity).
__global__ __launch_bounds__(256) void k_fused(
    const u16* __restrict__ adjb, const u16* __restrict__ mw2hi,
    const u16* __restrict__ mw2lo, const float* __restrict__ x,
    const float* __restrict__ W1, const float* __restrict__ posf,
    const float* __restrict__ negf, const float* __restrict__ uvb,
    float* __restrict__ out) {
    __shared__ __align__(16) u16 adjL[64 * 72];   // 9 KB
    __shared__ __align__(16) u16 mhiL[128 * 72];  // 18 KB
    __shared__ __align__(16) u16 mloL[128 * 72];  // 18 KB

    int bid = blockIdx.x;
    int vbid = ((bid & 7) << 5) | (bid >> 3);  // XCD chunking: 4 b's per XCD (r10 verbatim)
    int b = vbid >> 3;
    int j0 = (vbid & 7) * 64;
    int tx = threadIdx.x, lane = tx & 63, w = tx >> 6;

    const u16* adjrow = adjb + ((size_t)b * NN + j0) * NN;
    const u16* mhG = mw2hi + (size_t)b * PP * NN;
    const u16* mlG = mw2lo + (size_t)b * PP * NN;

    f32x4 acc[4][2];  // [jt][pt]
#pragma unroll
    for (int a = 0; a < 4; ++a)
#pragma unroll
        for (int c = 0; c < 2; ++c) acc[a][c] = (f32x4){0.f, 0.f, 0.f, 0.f};

    for (int step = 0; step < 8; ++step) {
        int k0 = step * 64;
        {  // stage adj tile 64x64 (r10 verbatim)
            int jj = tx >> 2, kk0 = (tx & 3) * 16;
            const uint4* src = (const uint4*)(adjrow + (size_t)jj * NN + k0 + kk0);
            uint4 v0 = src[0], v1 = src[1];
            *(uint4*)&adjL[jj * 72 + kk0] = v0;
            *(uint4*)&adjL[jj * 72 + kk0 + 8] = v1;
        }
        {  // stage muW2T hi/lo tiles 128x64 (r10 verbatim pattern)
            int p = tx >> 1, kk0 = (tx & 1) * 32;
            const uint4* sh = (const uint4*)(mhG + (size_t)p * NN + k0 + kk0);
            const uint4* sl = (const uint4*)(mlG + (size_t)p * NN + k0 + kk0);
#pragma unroll
            for (int c = 0; c < 4; ++c) {
                *(uint4*)&mhiL[p * 72 + kk0 + c * 8] = sh[c];
                *(uint4*)&mloL[p * 72 + kk0 + c * 8] = sl[c];
            }
        }
        __syncthreads();
#pragma unroll
        for (int ks = 0; ks < 2; ++ks) {
            int kb = ks * 32 + (lane >> 4) * 8;
            short8v afr[4];
#pragma unroll
            for (int jt = 0; jt < 4; ++jt)
                afr[jt] = *(const short8v*)&adjL[(jt * 16 + (lane & 15)) * 72 + kb];
#pragma unroll
            for (int pt = 0; pt < 2; ++pt) {
                int prow = w * 32 + pt * 16 + (lane & 15);
                short8v bh = *(const short8v*)&mhiL[prow * 72 + kb];
                short8v bl = *(const short8v*)&mloL[prow * 72 + kb];
#pragma unroll
                for (int jt = 0; jt < 4; ++jt) {
                    acc[jt][pt] = __builtin_amdgcn_mfma_f32_16x16x32_bf16(afr[jt], bh, acc[jt][pt], 0, 0, 0);
                    acc[jt][pt] = __builtin_amdgcn_mfma_f32_16x16x32_bf16(afr[jt], bl, acc[jt][pt], 0, 0, 0);
                }
            }
        }
        __syncthreads();
    }

    // epilogue (r10 verbatim form) — acc IS unit2 (fp32), no phase 2
    float u_[2], v_[2], bb_[2], w1_[2];
#pragma unroll
    for (int pt = 0; pt < 2; ++pt) {
        int pp = w * 32 + pt * 16 + (lane & 15);
        u_[pt] = uvb[pp];
        v_[pt] = uvb[PP + pp];
        bb_[pt] = uvb[2 * PP + pp];
        w1_[pt] = W1[pp];
    }
    int row0 = b * NN + j0;
#pragma unroll
    for (int jt = 0; jt < 4; ++jt)
#pragma unroll
        for (int r = 0; r < 4; ++r) {
            int row = row0 + jt * 16 + (lane >> 4) * 4 + r;
            float xs = x[row];
            float ps = posf[row];
            float ng = negf[row];
#pragma unroll
            for (int pt = 0; pt < 2; ++pt) {
                int pp = w * 32 + pt * 16 + (lane & 15);
                float o = acc[jt][pt][r] + xs * w1_[pt] + ps * u_[pt] + ng * v_[pt] + bb_[pt];
                out[(size_t)row * PP + pp] = fmaxf(o, 0.f);
            }
        }
}

extern "C" void kernel_launch(void* const* d_in, const int* in_sizes, int n_in,
                              void* d_out, int out_size, void* d_ws, size_t ws_size,
                              hipStream_t stream) {
    const float* x      = (const float*)d_in[0];
    const float* mu     = (const float*)d_in[1];
    const float* weight = (const float*)d_in[2];
    const float* adj    = (const float*)d_in[3];
    const float* W1     = (const float*)d_in[4];
    const float* b1     = (const float*)d_in[5];
    const float* W2     = (const float*)d_in[6];
    const float* b2     = (const float*)d_in[7];
    const float* W3     = (const float*)d_in[8];
    const float* b3     = (const float*)d_in[9];
    const float* theta4 = (const float*)d_in[10];
    float* out = (float*)d_out;

    float* ws   = (float*)d_ws;
    float* posP = ws + POSP_OFF;
    float* negP = ws + NEGP_OFF;
    float* uvb  = ws + UVB_OFF;
    float* posf = ws + PFIN_OFF;
    float* negf = ws + NFIN_OFF;
    u16* adjb   = (u16*)((char*)d_ws + ADJB_OFF);
    u16* muhi   = (u16*)((char*)d_ws + MUHI_OFF);
    u16* mulo   = (u16*)((char*)d_ws + MULO_OFF);
    u16* w2t    = (u16*)((char*)d_ws + W2T_OFF);
    u16* mw2hi  = (u16*)((char*)d_ws + MW2HI_OFF);
    u16* mw2lo  = (u16*)((char*)d_ws + MW2LO_OFF);

    dim3 gp(NN / 128, 8, BB);
    k_prep<<<gp, 512, 0, stream>>>(weight, adj, posP, negP, adjb);

    k_aux<<<74, 256, 0, stream>>>(mu, W2, theta4, W3, b1, b2, b3, posP, negP,
                                  posf, negf, uvb, muhi, mulo, w2t);

    k_muw2<<<256, 256, 0, stream>>>(w2t, muhi, mulo, mw2hi, mw2lo);

    k_fused<<<512 / 2, 256, 0, stream>>>(adjb, mw2hi, mw2lo, x, W1, posf, negf,
                                         uvb, out);
}

// Round 13
// 50.108 us; speedup vs baseline: 1.5780x; 1.5780x over previous
//
#include <hip/hip_runtime.h>

#define BB 32
#define NN 512
#define PP 128
#define MM (BB * NN)  // 16384 rows

typedef unsigned int u32;
typedef unsigned short u16;

typedef __attribute__((ext_vector_type(8))) short short8v;  // 8 bf16 (4 VGPR)
typedef __attribute__((ext_vector_type(4))) float f32x4;

// ---- ws layout (r10 lineage) ----
#define POSP_OFF 0                      // [8][MM] f32
#define NEGP_OFF (8 * MM)               // [8][MM] f32
#define UVB_OFF (16 * MM)               // u[128], v[128], bias[128]
#define PFIN_OFF (16 * MM + 512)        // pos final [MM]
#define NFIN_OFF (16 * MM + 512 + MM)   // neg final [MM]
#define MUTHI_OFF ((size_t)20971520)    // u16 [BB][PP][NN] = 4 MB (muT hi)
#define MUTLO_OFF ((size_t)25165824)    // u16 [BB][PP][NN] = 4 MB (muT lo)
#define W2T_OFF ((size_t)29360128)      // u16 [PP][PP] = 32 KB (W2T[p][q]=bf16(W2[q][p]))

__device__ inline u32 bf16rne(float f) {
    u32 u = __float_as_uint(f);
    return (u + 0x7FFFu + ((u >> 16) & 1u)) >> 16;
}

// prep (r10 minus the adjb store): pos/neg partials only.
__global__ __launch_bounds__(512) void k_prep(const float* __restrict__ weight,
                                              const float* __restrict__ adj,
                                              float* __restrict__ posP,
                                              float* __restrict__ negP) {
    __shared__ float sps[8][128], sng[8][128];

    int b = blockIdx.z, seg = blockIdx.y;
    int tx = threadIdx.x;
    int jl2 = tx & 63;
    int g = tx >> 6;
    int j0tile = blockIdx.x * 128;
    int j = j0tile + jl2 * 2;

    size_t base = (size_t)b * NN * NN + ((size_t)seg * 64 + g * 8) * NN + j;
    const float2* wp = (const float2*)(weight + base);
    const float2* ap = (const float2*)(adj + base);
    float psx = 0.f, psy = 0.f, ngx = 0.f, ngy = 0.f;
#pragma unroll
    for (int k = 0; k < 8; ++k) {
        float2 a = ap[(size_t)k * (NN / 2)];
        float2 w = wp[(size_t)k * (NN / 2)];
        float wa0 = w.x * a.x;
        float wa1 = w.y * a.y;
        psx += fmaxf(wa0, 0.f);
        ngx += fmaxf(-wa0, 0.f);
        psy += fmaxf(wa1, 0.f);
        ngy += fmaxf(-wa1, 0.f);
    }
    sps[g][2 * jl2] = psx;
    sps[g][2 * jl2 + 1] = psy;
    sng[g][2 * jl2] = ngx;
    sng[g][2 * jl2 + 1] = ngy;
    __syncthreads();
    if (tx < 128) {
        float P = 0.f, Ng = 0.f;
#pragma unroll
        for (int g2 = 0; g2 < 8; ++g2) {
            P += sps[g2][tx];
            Ng += sng[g2][tx];
        }
        int row = b * NN + j0tile + tx;
        posP[seg * MM + row] = P;
        negP[seg * MM + row] = Ng;
    }
}

// aux (r10 verbatim): bid<256: mu transpose -> muT hi/lo bf16; 256..263:
// pos/neg reduce; 264: uv+bias; 265: W2T bf16.
__global__ __launch_bounds__(256) void k_aux(
    const float* __restrict__ mu, const float* __restrict__ W2,
    const float* __restrict__ t4, const float* __restrict__ W3,
    const float* __restrict__ b1, const float* __restrict__ b2,
    const float* __restrict__ b3, const float* __restrict__ posP,
    const float* __restrict__ negP, float* __restrict__ posf,
    float* __restrict__ negf, float* __restrict__ uvb,
    u16* __restrict__ muthi, u16* __restrict__ mutlo, u16* __restrict__ w2t) {
    __shared__ float tile[64][132];
    __shared__ float su[2][PP], sv[2][PP];
    int bid = blockIdx.x;
    int t = threadIdx.x;
    if (bid < 256) {
        int b = bid >> 3, i0 = (bid & 7) * 64;
        const float4* mu4 = (const float4*)(mu + ((size_t)b * NN + i0) * PP);
#pragma unroll
        for (int s = 0; s < 8; ++s) {
            int n = s * 256 + t;
            int ii = n >> 5, c4 = n & 31;
            float4 v = mu4[ii * 32 + c4];
            *(float4*)&tile[ii][c4 * 4] = v;
        }
        __syncthreads();
        int p = t >> 1, half = t & 1;
        u32* hdst = (u32*)(muthi + ((size_t)b * PP + p) * NN + i0 + half * 32);
        u32* ldst = (u32*)(mutlo + ((size_t)b * PP + p) * NN + i0 + half * 32);
#pragma unroll
        for (int e2 = 0; e2 < 16; ++e2) {
            float v0 = tile[half * 32 + 2 * e2][p];
            float v1 = tile[half * 32 + 2 * e2 + 1][p];
            u32 h0 = bf16rne(v0), h1 = bf16rne(v1);
            float l0 = v0 - __uint_as_float(h0 << 16);
            float l1 = v1 - __uint_as_float(h1 << 16);
            hdst[e2] = h0 | (h1 << 16);
            ldst[e2] = bf16rne(l0) | (bf16rne(l1) << 16);
        }
    } else if (bid < 264) {
        int base = (bid - 256) * 2048;
#pragma unroll
        for (int rr = 0; rr < 8; ++rr) {
            int row = base + rr * 256 + t;
            float P = 0.f, Ng = 0.f;
#pragma unroll
            for (int s = 0; s < 8; ++s) {
                P += posP[s * MM + row];
                Ng += negP[s * MM + row];
            }
            posf[row] = P;
            negf[row] = Ng;
        }
    } else if (bid == 264) {
        int p = t & 127, h = t >> 7;
        float u = 0.f, v = 0.f;
#pragma unroll 8
        for (int q = h * 64; q < h * 64 + 64; ++q) {
            float tt = t4[q];
            float w = W3[q * PP + p];
            u += fmaxf(tt, 0.f) * w;
            v += fmaxf(-tt, 0.f) * w;
        }
        su[h][p] = u;
        sv[h][p] = v;
        __syncthreads();
        if (t < PP) {
            uvb[p] = su[0][p] + su[1][p];
            uvb[PP + p] = sv[0][p] + sv[1][p];
            uvb[2 * PP + p] = b1[p] + b2[p] + b3[p];
        }
    } else {
#pragma unroll 4
        for (int c = 0; c < 64; ++c) {
            int n = c * 256 + t;
            int q = n >> 7, pp = n & 127;
            w2t[pp * PP + q] = (u16)bf16rne(W2[q * PP + pp]);
        }
    }
}

// fused (r10 verbatim EXCEPT adj staged directly from f32 input, bf16-inline):
// agg = adj @ mu via MFMA (mu hi/lo), agg hi/lo -> LDS,
// out = relu(agg@W2 (MFMA, W2T bf16) + x*W1 + pos*u + neg*v + bias).
// 256 blocks = 32 b x 8 jtiles(64). 256 thr = 4 waves; wave w owns p-slice [32w,32w+32).
__global__ __launch_bounds__(256) void k_fused(
    const float* __restrict__ adjF, const u16* __restrict__ muthi,
    const u16* __restrict__ mutlo, const u16* __restrict__ w2t,
    const float* __restrict__ x, const float* __restrict__ W1,
    const float* __restrict__ posf, const float* __restrict__ negf,
    const float* __restrict__ uvb, float* __restrict__ out) {
    __shared__ __align__(16) u16 pool[32768];  // 64 KB
    // phase1 carve: adjL [64][72] @0; muhiL [128][72] @4608; muloL [128][72] @13824
    u16* adjL = pool;
    u16* mhiL = pool + 4608;
    u16* mloL = pool + 13824;
    // phase2 carve (aliases, barrier-separated): w2L [128][128 swz] @0;
    // agghi [64][128 swz] @16384; agglo @24576
    u16* w2L = pool;
    u16* ahiL = pool + 16384;
    u16* aloL = pool + 24576;

    int bid = blockIdx.x;
    int vbid = ((bid & 7) << 5) | (bid >> 3);  // XCD chunking: 4 b's per XCD
    int b = vbid >> 3;
    int j0 = (vbid & 7) * 64;
    int tx = threadIdx.x, lane = tx & 63, w = tx >> 6;

    const float* adjrow = adjF + ((size_t)b * NN + j0) * NN;
    const u16* mhG = muthi + (size_t)b * PP * NN;
    const u16* mlG = mutlo + (size_t)b * PP * NN;

    f32x4 acc[4][2];  // [jt][pt]
#pragma unroll
    for (int a = 0; a < 4; ++a)
#pragma unroll
        for (int c = 0; c < 2; ++c) acc[a][c] = (f32x4){0.f, 0.f, 0.f, 0.f};

    for (int step = 0; step < 8; ++step) {
        int k0 = step * 64;
        {  // stage adj tile 64x64 from f32, inline 0/1 -> bf16 (exact)
            int jj = tx >> 2, kk0 = (tx & 3) * 16;
            const float4* src = (const float4*)(adjrow + (size_t)jj * NN + k0 + kk0);
            float4 f0 = src[0], f1 = src[1], f2 = src[2], f3 = src[3];
            uint4 o0, o1;
            o0.x = (f0.x != 0.f ? 0x3F80u : 0u) | (f0.y != 0.f ? 0x3F800000u : 0u);
            o0.y = (f0.z != 0.f ? 0x3F80u : 0u) | (f0.w != 0.f ? 0x3F800000u : 0u);
            o0.z = (f1.x != 0.f ? 0x3F80u : 0u) | (f1.y != 0.f ? 0x3F800000u : 0u);
            o0.w = (f1.z != 0.f ? 0x3F80u : 0u) | (f1.w != 0.f ? 0x3F800000u : 0u);
            o1.x = (f2.x != 0.f ? 0x3F80u : 0u) | (f2.y != 0.f ? 0x3F800000u : 0u);
            o1.y = (f2.z != 0.f ? 0x3F80u : 0u) | (f2.w != 0.f ? 0x3F800000u : 0u);
            o1.z = (f3.x != 0.f ? 0x3F80u : 0u) | (f3.y != 0.f ? 0x3F800000u : 0u);
            o1.w = (f3.z != 0.f ? 0x3F80u : 0u) | (f3.w != 0.f ? 0x3F800000u : 0u);
            *(uint4*)&adjL[jj * 72 + kk0] = o0;
            *(uint4*)&adjL[jj * 72 + kk0 + 8] = o1;
        }
        {  // stage muT hi/lo tiles 128x64 (r10 verbatim)
            int p = tx >> 1, kk0 = (tx & 1) * 32;
            const uint4* sh = (const uint4*)(mhG + (size_t)p * NN + k0 + kk0);
            const uint4* sl = (const uint4*)(mlG + (size_t)p * NN + k0 + kk0);
#pragma unroll
            for (int c = 0; c < 4; ++c) {
                *(uint4*)&mhiL[p * 72 + kk0 + c * 8] = sh[c];
                *(uint4*)&mloL[p * 72 + kk0 + c * 8] = sl[c];
            }
        }
        __syncthreads();
#pragma unroll
        for (int ks = 0; ks < 2; ++ks) {
            int kb = ks * 32 + (lane >> 4) * 8;
            short8v afr[4];
#pragma unroll
            for (int jt = 0; jt < 4; ++jt)
                afr[jt] = *(const short8v*)&adjL[(jt * 16 + (lane & 15)) * 72 + kb];
#pragma unroll
            for (int pt = 0; pt < 2; ++pt) {
                int prow = w * 32 + pt * 16 + (lane & 15);
                short8v bh = *(const short8v*)&mhiL[prow * 72 + kb];
                short8v bl = *(const short8v*)&mloL[prow * 72 + kb];
#pragma unroll
                for (int jt = 0; jt < 4; ++jt) {
                    acc[jt][pt] = __builtin_amdgcn_mfma_f32_16x16x32_bf16(afr[jt], bh, acc[jt][pt], 0, 0, 0);
                    acc[jt][pt] = __builtin_amdgcn_mfma_f32_16x16x32_bf16(afr[jt], bl, acc[jt][pt], 0, 0, 0);
                }
            }
        }
        __syncthreads();
    }

    // acc -> agg hi/lo (XOR-swizzled cols) ; stage W2T (same swizzle) (r10 verbatim)
    {
#pragma unroll
        for (int jt = 0; jt < 4; ++jt)
#pragma unroll
            for (int pt = 0; pt < 2; ++pt)
#pragma unroll
                for (int r = 0; r < 4; ++r) {
                    int j = jt * 16 + (lane >> 4) * 4 + r;
                    int q = w * 32 + pt * 16 + (lane & 15);
                    float v = acc[jt][pt][r];
                    u32 h = bf16rne(v);
                    float lf = v - __uint_as_float(h << 16);
                    int qs = q ^ ((j & 7) << 3);
                    ahiL[j * 128 + qs] = (u16)h;
                    aloL[j * 128 + qs] = (u16)bf16rne(lf);
                }
        int p = tx >> 1, qc = (tx & 1) * 64;
        const uint4* src = (const uint4*)(w2t + p * PP + qc);
#pragma unroll
        for (int c = 0; c < 8; ++c) {
            int q8 = (qc + c * 8) ^ ((p & 7) << 3);
            *(uint4*)&w2L[p * 128 + q8] = src[c];
        }
    }
    __syncthreads();

    // phase 2 (r10 verbatim): D2[j][p'] = sum_q agg[j][q] * W2[q][p']
    f32x4 acc2[4][2];  // [jt][nt]
#pragma unroll
    for (int a = 0; a < 4; ++a)
#pragma unroll
        for (int c = 0; c < 2; ++c) acc2[a][c] = (f32x4){0.f, 0.f, 0.f, 0.f};
#pragma unroll
    for (int ks = 0; ks < 4; ++ks) {
        int kb = ks * 32 + (lane >> 4) * 8;
        short8v bfr[2];
#pragma unroll
        for (int nt = 0; nt < 2; ++nt) {
            int prow = w * 32 + nt * 16 + (lane & 15);
            bfr[nt] = *(const short8v*)&w2L[prow * 128 + (kb ^ ((prow & 7) << 3))];
        }
#pragma unroll
        for (int jt = 0; jt < 4; ++jt) {
            int jrow = jt * 16 + (lane & 15);
            short8v ah = *(const short8v*)&ahiL[jrow * 128 + (kb ^ ((jrow & 7) << 3))];
            short8v al = *(const short8v*)&aloL[jrow * 128 + (kb ^ ((jrow & 7) << 3))];
#pragma unroll
            for (int nt = 0; nt < 2; ++nt) {
                acc2[jt][nt] = __builtin_amdgcn_mfma_f32_16x16x32_bf16(ah, bfr[nt], acc2[jt][nt], 0, 0, 0);
                acc2[jt][nt] = __builtin_amdgcn_mfma_f32_16x16x32_bf16(al, bfr[nt], acc2[jt][nt], 0, 0, 0);
            }
        }
    }

    // epilogue (r10 verbatim)
    float u_[2], v_[2], bb_[2], w1_[2];
#pragma unroll
    for (int nt = 0; nt < 2; ++nt) {
        int pp = w * 32 + nt * 16 + (lane & 15);
        u_[nt] = uvb[pp];
        v_[nt] = uvb[PP + pp];
        bb_[nt] = uvb[2 * PP + pp];
        w1_[nt] = W1[pp];
    }
    int row0 = b * NN + j0;
#pragma unroll
    for (int jt = 0; jt < 4; ++jt)
#pragma unroll
        for (int r = 0; r < 4; ++r) {
            int row = row0 + jt * 16 + (lane >> 4) * 4 + r;
            float xs = x[row];
            float ps = posf[row];
            float ng = negf[row];
#pragma unroll
            for (int nt = 0; nt < 2; ++nt) {
                int pp = w * 32 + nt * 16 + (lane & 15);
                float o = acc2[jt][nt][r] + xs * w1_[nt] + ps * u_[nt] + ng * v_[nt] + bb_[nt];
                out[(size_t)row * PP + pp] = fmaxf(o, 0.f);
            }
        }
}

extern "C" void kernel_launch(void* const* d_in, const int* in_sizes, int n_in,
                              void* d_out, int out_size, void* d_ws, size_t ws_size,
                              hipStream_t stream) {
    const float* x      = (const float*)d_in[0];
    const float* mu     = (const float*)d_in[1];
    const float* weight = (const float*)d_in[2];
    const float* adj    = (const float*)d_in[3];
    const float* W1     = (const float*)d_in[4];
    const float* b1     = (const float*)d_in[5];
    const float* W2     = (const float*)d_in[6];
    const float* b2     = (const float*)d_in[7];
    const float* W3     = (const float*)d_in[8];
    const float* b3     = (const float*)d_in[9];
    const float* theta4 = (const float*)d_in[10];
    float* out = (float*)d_out;

    float* ws   = (float*)d_ws;
    float* posP = ws + POSP_OFF;
    float* negP = ws + NEGP_OFF;
    float* uvb  = ws + UVB_OFF;
    float* posf = ws + PFIN_OFF;
    float* negf = ws + NFIN_OFF;
    u16* muthi  = (u16*)((char*)d_ws + MUTHI_OFF);
    u16* mutlo  = (u16*)((char*)d_ws + MUTLO_OFF);
    u16* w2t    = (u16*)((char*)d_ws + W2T_OFF);

    dim3 gp(NN / 128, 8, BB);
    k_prep<<<gp, 512, 0, stream>>>(weight, adj, posP, negP);

    k_aux<<<266, 256, 0, stream>>>(mu, W2, theta4, W3, b1, b2, b3, posP, negP,
                                   posf, negf, uvb, muthi, mutlo, w2t);

    k_fused<<<256, 256, 0, stream>>>(adj, muthi, mutlo, w2t, x, W1, posf, negf,
                                     uvb, out);
}

// Round 14
// 47.489 us; speedup vs baseline: 1.6650x; 1.0552x over previous
//
#include <hip/hip_runtime.h>

#define BB 32
#define NN 512
#define PP 128
#define MM (BB * NN)  // 16384 rows

typedef unsigned int u32;
typedef unsigned short u16;

typedef __attribute__((ext_vector_type(8))) short short8v;  // 8 bf16 (4 VGPR)
typedef __attribute__((ext_vector_type(4))) float f32x4;

// ---- ws layout (r13 lineage; prep arrays deleted) ----
#define UVB_OFF (16 * MM)               // u[128], v[128], bias[128]
#define MUTHI_OFF ((size_t)20971520)    // u16 [BB][PP][NN] = 4 MB (muT hi)
#define MUTLO_OFF ((size_t)25165824)    // u16 [BB][PP][NN] = 4 MB (muT lo)
#define W2T_OFF ((size_t)29360128)      // u16 [PP][PP] = 32 KB (W2T[p][q]=bf16(W2[q][p]))

__device__ inline u32 bf16rne(float f) {
    u32 u = __float_as_uint(f);
    return (u + 0x7FFFu + ((u >> 16) & 1u)) >> 16;
}

// aux (r13 minus the posP-reduce role): bid<256: mu transpose -> muT hi/lo bf16;
// 256: uv+bias; 257: W2T bf16.
__global__ __launch_bounds__(256) void k_aux(
    const float* __restrict__ mu, const float* __restrict__ W2,
    const float* __restrict__ t4, const float* __restrict__ W3,
    const float* __restrict__ b1, const float* __restrict__ b2,
    const float* __restrict__ b3, float* __restrict__ uvb,
    u16* __restrict__ muthi, u16* __restrict__ mutlo, u16* __restrict__ w2t) {
    __shared__ float tile[64][132];
    __shared__ float su[2][PP], sv[2][PP];
    int bid = blockIdx.x;
    int t = threadIdx.x;
    if (bid < 256) {
        int b = bid >> 3, i0 = (bid & 7) * 64;
        const float4* mu4 = (const float4*)(mu + ((size_t)b * NN + i0) * PP);
#pragma unroll
        for (int s = 0; s < 8; ++s) {
            int n = s * 256 + t;
            int ii = n >> 5, c4 = n & 31;
            float4 v = mu4[ii * 32 + c4];
            *(float4*)&tile[ii][c4 * 4] = v;
        }
        __syncthreads();
        int p = t >> 1, half = t & 1;
        u32* hdst = (u32*)(muthi + ((size_t)b * PP + p) * NN + i0 + half * 32);
        u32* ldst = (u32*)(mutlo + ((size_t)b * PP + p) * NN + i0 + half * 32);
#pragma unroll
        for (int e2 = 0; e2 < 16; ++e2) {
            float v0 = tile[half * 32 + 2 * e2][p];
            float v1 = tile[half * 32 + 2 * e2 + 1][p];
            u32 h0 = bf16rne(v0), h1 = bf16rne(v1);
            float l0 = v0 - __uint_as_float(h0 << 16);
            float l1 = v1 - __uint_as_float(h1 << 16);
            hdst[e2] = h0 | (h1 << 16);
            ldst[e2] = bf16rne(l0) | (bf16rne(l1) << 16);
        }
    } else if (bid == 256) {
        int p = t & 127, h = t >> 7;
        float u = 0.f, v = 0.f;
#pragma unroll 8
        for (int q = h * 64; q < h * 64 + 64; ++q) {
            float tt = t4[q];
            float w = W3[q * PP + p];
            u += fmaxf(tt, 0.f) * w;
            v += fmaxf(-tt, 0.f) * w;
        }
        su[h][p] = u;
        sv[h][p] = v;
        __syncthreads();
        if (t < PP) {
            uvb[p] = su[0][p] + su[1][p];
            uvb[PP + p] = sv[0][p] + sv[1][p];
            uvb[2 * PP + p] = b1[p] + b2[p] + b3[p];
        }
    } else {
#pragma unroll 4
        for (int c = 0; c < 64; ++c) {
            int n = c * 256 + t;
            int q = n >> 7, pp = n & 127;
            w2t[pp * PP + q] = (u16)bf16rne(W2[q * PP + pp]);
        }
    }
}

// fused: agg = adj @ mu (MFMA, hi/lo), POS/NEG INLINE (weight col-slices
// during staging), agg hi/lo -> LDS, @W2 (MFMA), epilogue.
// 512 blocks = 32 b x 16 j-tiles(32). 256 thr = 4 waves; wave w: p-slice 32.
__global__ __launch_bounds__(256) void k_fused(
    const float* __restrict__ adjF, const float* __restrict__ weight,
    const u16* __restrict__ muthi, const u16* __restrict__ mutlo,
    const u16* __restrict__ w2t, const float* __restrict__ x,
    const float* __restrict__ W1, const float* __restrict__ uvb,
    float* __restrict__ out) {
    __shared__ __align__(16) u16 pool[24576];  // 48 KB
    // phase1 carve: adjL [32][72] @0; mhiL [128][72] @2304; mloL @11520
    u16* adjL = pool;
    u16* mhiL = pool + 2304;
    u16* mloL = pool + 11520;
    // phase2 carve (aliases, barrier-separated): w2L [128][128 swz] @0;
    // ahiL [32][128 swz] @16384; aloL @20480
    u16* w2L = pool;
    u16* ahiL = pool + 16384;
    u16* aloL = pool + 20480;
    __shared__ float psP[8][32], ngP[8][32];
    __shared__ float psF[32], ngF[32];

    int bid = blockIdx.x;
    int vbid = ((bid & 7) << 6) | (bid >> 3);  // XCD chunking (bijective)
    int b = vbid >> 4;
    int j0 = (vbid & 15) * 32;
    int tx = threadIdx.x, lane = tx & 63, w = tx >> 6;

    const float* adjrow = adjF + ((size_t)b * NN + j0) * NN;       // [j][i] rows
    const float* adjcol = adjF + (size_t)b * NN * NN + j0;          // [i][j] cols
    const float* wcol = weight + (size_t)b * NN * NN + j0;          // [i][j] cols
    const u16* mhG = muthi + (size_t)b * PP * NN;
    const u16* mlG = mutlo + (size_t)b * PP * NN;

    // pos/neg thread mapping: jw = tx&31, kgrp = tx>>5 (8 i's per step)
    int jw = tx & 31, kgrp = tx >> 5;
    float ps = 0.f, ng = 0.f;

    f32x4 acc[2][2];  // [jt][pt]
#pragma unroll
    for (int a = 0; a < 2; ++a)
#pragma unroll
        for (int c = 0; c < 2; ++c) acc[a][c] = (f32x4){0.f, 0.f, 0.f, 0.f};

    for (int step = 0; step < 8; ++step) {
        int k0 = step * 64;
        {  // stage adj tile 32x64 from f32, inline 0/1 -> bf16 (exact)
            int jj = tx >> 3, kk0 = (tx & 7) * 8;
            const float4* src = (const float4*)(adjrow + (size_t)jj * NN + k0 + kk0);
            float4 f0 = src[0], f1 = src[1];
            uint4 o0;
            o0.x = (f0.x != 0.f ? 0x3F80u : 0u) | (f0.y != 0.f ? 0x3F800000u : 0u);
            o0.y = (f0.z != 0.f ? 0x3F80u : 0u) | (f0.w != 0.f ? 0x3F800000u : 0u);
            o0.z = (f1.x != 0.f ? 0x3F80u : 0u) | (f1.y != 0.f ? 0x3F800000u : 0u);
            o0.w = (f1.z != 0.f ? 0x3F80u : 0u) | (f1.w != 0.f ? 0x3F800000u : 0u);
            *(uint4*)&adjL[jj * 72 + kk0] = o0;
        }
        {  // stage muT hi/lo tiles 128x64 (r13 verbatim)
            int p = tx >> 1, kk0 = (tx & 1) * 32;
            const uint4* sh = (const uint4*)(mhG + (size_t)p * NN + k0 + kk0);
            const uint4* sl = (const uint4*)(mlG + (size_t)p * NN + k0 + kk0);
#pragma unroll
            for (int c = 0; c < 4; ++c) {
                *(uint4*)&mhiL[p * 72 + kk0 + c * 8] = sh[c];
                *(uint4*)&mloL[p * 72 + kk0 + c * 8] = sl[c];
            }
        }
        {  // inline pos/neg: weight+adj column slices (coalesced 128B segments)
#pragma unroll
            for (int kk = 0; kk < 8; ++kk) {
                size_t off = (size_t)(k0 + kgrp * 8 + kk) * NN + jw;
                float wv = wcol[off];
                float av = adjcol[off];  // exactly 0.0 or 1.0
                ps += fmaxf(wv, 0.f) * av;
                ng += fmaxf(-wv, 0.f) * av;
            }
        }
        __syncthreads();
#pragma unroll
        for (int ks = 0; ks < 2; ++ks) {
            int kb = ks * 32 + (lane >> 4) * 8;
            short8v afr[2];
#pragma unroll
            for (int jt = 0; jt < 2; ++jt)
                afr[jt] = *(const short8v*)&adjL[(jt * 16 + (lane & 15)) * 72 + kb];
#pragma unroll
            for (int pt = 0; pt < 2; ++pt) {
                int prow = w * 32 + pt * 16 + (lane & 15);
                short8v bh = *(const short8v*)&mhiL[prow * 72 + kb];
                short8v bl = *(const short8v*)&mloL[prow * 72 + kb];
#pragma unroll
                for (int jt = 0; jt < 2; ++jt) {
                    acc[jt][pt] = __builtin_amdgcn_mfma_f32_16x16x32_bf16(afr[jt], bh, acc[jt][pt], 0, 0, 0);
                    acc[jt][pt] = __builtin_amdgcn_mfma_f32_16x16x32_bf16(afr[jt], bl, acc[jt][pt], 0, 0, 0);
                }
            }
        }
        __syncthreads();
    }

    // pos/neg partials -> LDS; acc -> agg hi/lo (XOR-swz); stage W2T (same swz)
    psP[kgrp][jw] = ps;
    ngP[kgrp][jw] = ng;
    {
#pragma unroll
        for (int jt = 0; jt < 2; ++jt)
#pragma unroll
            for (int pt = 0; pt < 2; ++pt)
#pragma unroll
                for (int r = 0; r < 4; ++r) {
                    int j = jt * 16 + (lane >> 4) * 4 + r;
                    int q = w * 32 + pt * 16 + (lane & 15);
                    float v = acc[jt][pt][r];
                    u32 h = bf16rne(v);
                    float lf = v - __uint_as_float(h << 16);
                    int qs = q ^ ((j & 7) << 3);
                    ahiL[j * 128 + qs] = (u16)h;
                    aloL[j * 128 + qs] = (u16)bf16rne(lf);
                }
        int p = tx >> 1, qc = (tx & 1) * 64;
        const uint4* src = (const uint4*)(w2t + p * PP + qc);
#pragma unroll
        for (int c = 0; c < 8; ++c) {
            int q8 = (qc + c * 8) ^ ((p & 7) << 3);
            *(uint4*)&w2L[p * 128 + q8] = src[c];
        }
    }
    __syncthreads();

    // final pos/neg reduce (32 threads) while others start phase 2
    if (tx < 32) {
        float P = 0.f, Ng = 0.f;
#pragma unroll
        for (int g = 0; g < 8; ++g) {
            P += psP[g][tx];
            Ng += ngP[g][tx];
        }
        psF[tx] = P;
        ngF[tx] = Ng;
    }

    // phase 2 (r13 verbatim, jt: 2): D2[j][p'] = sum_q agg[j][q] * W2[q][p']
    f32x4 acc2[2][2];  // [jt][nt]
#pragma unroll
    for (int a = 0; a < 2; ++a)
#pragma unroll
        for (int c = 0; c < 2; ++c) acc2[a][c] = (f32x4){0.f, 0.f, 0.f, 0.f};
#pragma unroll
    for (int ks = 0; ks < 4; ++ks) {
        int kb = ks * 32 + (lane >> 4) * 8;
        short8v bfr[2];
#pragma unroll
        for (int nt = 0; nt < 2; ++nt) {
            int prow = w * 32 + nt * 16 + (lane & 15);
            bfr[nt] = *(const short8v*)&w2L[prow * 128 + (kb ^ ((prow & 7) << 3))];
        }
#pragma unroll
        for (int jt = 0; jt < 2; ++jt) {
            int jrow = jt * 16 + (lane & 15);
            short8v ah = *(const short8v*)&ahiL[jrow * 128 + (kb ^ ((jrow & 7) << 3))];
            short8v al = *(const short8v*)&aloL[jrow * 128 + (kb ^ ((jrow & 7) << 3))];
#pragma unroll
            for (int nt = 0; nt < 2; ++nt) {
                acc2[jt][nt] = __builtin_amdgcn_mfma_f32_16x16x32_bf16(ah, bfr[nt], acc2[jt][nt], 0, 0, 0);
                acc2[jt][nt] = __builtin_amdgcn_mfma_f32_16x16x32_bf16(al, bfr[nt], acc2[jt][nt], 0, 0, 0);
            }
        }
    }
    __syncthreads();  // psF/ngF visible to all

    // epilogue (r13 form; ps/ng from LDS)
    float u_[2], v_[2], bb_[2], w1_[2];
#pragma unroll
    for (int nt = 0; nt < 2; ++nt) {
        int pp = w * 32 + nt * 16 + (lane & 15);
        u_[nt] = uvb[pp];
        v_[nt] = uvb[PP + pp];
        bb_[nt] = uvb[2 * PP + pp];
        w1_[nt] = W1[pp];
    }
    int row0 = b * NN + j0;
#pragma unroll
    for (int jt = 0; jt < 2; ++jt)
#pragma unroll
        for (int r = 0; r < 4; ++r) {
            int jloc = jt * 16 + (lane >> 4) * 4 + r;
            int row = row0 + jloc;
            float xs = x[row];
            float pss = psF[jloc];
            float ngg = ngF[jloc];
#pragma unroll
            for (int nt = 0; nt < 2; ++nt) {
                int pp = w * 32 + nt * 16 + (lane & 15);
                float o = acc2[jt][nt][r] + xs * w1_[nt] + pss * u_[nt] + ngg * v_[nt] + bb_[nt];
                out[(size_t)row * PP + pp] = fmaxf(o, 0.f);
            }
        }
}

extern "C" void kernel_launch(void* const* d_in, const int* in_sizes, int n_in,
                              void* d_out, int out_size, void* d_ws, size_t ws_size,
                              hipStream_t stream) {
    const float* x      = (const float*)d_in[0];
    const float* mu     = (const float*)d_in[1];
    const float* weight = (const float*)d_in[2];
    const float* adj    = (const float*)d_in[3];
    const float* W1     = (const float*)d_in[4];
    const float* b1     = (const float*)d_in[5];
    const float* W2     = (const float*)d_in[6];
    const float* b2     = (const float*)d_in[7];
    const float* W3     = (const float*)d_in[8];
    const float* b3     = (const float*)d_in[9];
    const float* theta4 = (const float*)d_in[10];
    float* out = (float*)d_out;

    float* ws  = (float*)d_ws;
    float* uvb = ws + UVB_OFF;
    u16* muthi = (u16*)((char*)d_ws + MUTHI_OFF);
    u16* mutlo = (u16*)((char*)d_ws + MUTLO_OFF);
    u16* w2t   = (u16*)((char*)d_ws + W2T_OFF);

    k_aux<<<258, 256, 0, stream>>>(mu, W2, theta4, W3, b1, b2, b3, uvb,
                                   muthi, mutlo, w2t);

    k_fused<<<512, 256, 0, stream>>>(adj, weight, muthi, mutlo, w2t, x, W1,
                                     uvb, out);
}

// Round 15
// 41.486 us; speedup vs baseline: 1.9059x; 1.1447x over previous
//
#include <hip/hip_runtime.h>

#define BB 32
#define NN 512
#define PP 128
#define MM (BB * NN)  // 16384 rows

typedef unsigned int u32;
typedef unsigned short u16;

typedef __attribute__((ext_vector_type(8))) short short8v;  // 8 bf16 (4 VGPR)
typedef __attribute__((ext_vector_type(4))) float f32x4;

// ---- ws layout (r14 verbatim) ----
#define UVB_OFF (16 * MM)               // u[128], v[128], bias[128]
#define MUTHI_OFF ((size_t)20971520)    // u16 [BB][PP][NN] = 4 MB (muT hi)
#define MUTLO_OFF ((size_t)25165824)    // u16 [BB][PP][NN] = 4 MB (muT lo)
#define W2T_OFF ((size_t)29360128)      // u16 [PP][PP] = 32 KB (W2T[p][q]=bf16(W2[q][p]))

__device__ inline u32 bf16rne(float f) {
    u32 u = __float_as_uint(f);
    return (u + 0x7FFFu + ((u >> 16) & 1u)) >> 16;
}

// aux (r14 verbatim): bid<256: mu transpose -> muT hi/lo bf16; 256: uv+bias;
// 257: W2T bf16.
__global__ __launch_bounds__(256) void k_aux(
    const float* __restrict__ mu, const float* __restrict__ W2,
    const float* __restrict__ t4, const float* __restrict__ W3,
    const float* __restrict__ b1, const float* __restrict__ b2,
    const float* __restrict__ b3, float* __restrict__ uvb,
    u16* __restrict__ muthi, u16* __restrict__ mutlo, u16* __restrict__ w2t) {
    __shared__ float tile[64][132];
    __shared__ float su[2][PP], sv[2][PP];
    int bid = blockIdx.x;
    int t = threadIdx.x;
    if (bid < 256) {
        int b = bid >> 3, i0 = (bid & 7) * 64;
        const float4* mu4 = (const float4*)(mu + ((size_t)b * NN + i0) * PP);
#pragma unroll
        for (int s = 0; s < 8; ++s) {
            int n = s * 256 + t;
            int ii = n >> 5, c4 = n & 31;
            float4 v = mu4[ii * 32 + c4];
            *(float4*)&tile[ii][c4 * 4] = v;
        }
        __syncthreads();
        int p = t >> 1, half = t & 1;
        u32* hdst = (u32*)(muthi + ((size_t)b * PP + p) * NN + i0 + half * 32);
        u32* ldst = (u32*)(mutlo + ((size_t)b * PP + p) * NN + i0 + half * 32);
#pragma unroll
        for (int e2 = 0; e2 < 16; ++e2) {
            float v0 = tile[half * 32 + 2 * e2][p];
            float v1 = tile[half * 32 + 2 * e2 + 1][p];
            u32 h0 = bf16rne(v0), h1 = bf16rne(v1);
            float l0 = v0 - __uint_as_float(h0 << 16);
            float l1 = v1 - __uint_as_float(h1 << 16);
            hdst[e2] = h0 | (h1 << 16);
            ldst[e2] = bf16rne(l0) | (bf16rne(l1) << 16);
        }
    } else if (bid == 256) {
        int p = t & 127, h = t >> 7;
        float u = 0.f, v = 0.f;
#pragma unroll 8
        for (int q = h * 64; q < h * 64 + 64; ++q) {
            float tt = t4[q];
            float w = W3[q * PP + p];
            u += fmaxf(tt, 0.f) * w;
            v += fmaxf(-tt, 0.f) * w;
        }
        su[h][p] = u;
        sv[h][p] = v;
        __syncthreads();
        if (t < PP) {
            uvb[p] = su[0][p] + su[1][p];
            uvb[PP + p] = sv[0][p] + sv[1][p];
            uvb[2 * PP + p] = b1[p] + b2[p] + b3[p];
        }
    } else {
#pragma unroll 4
        for (int c = 0; c < 64; ++c) {
            int n = c * 256 + t;
            int q = n >> 7, pp = n & 127;
            w2t[pp * PP + q] = (u16)bf16rne(W2[q * PP + pp]);
        }
    }
}

// fused (r14 structure, 512 thr / 8 waves, per-wave p-slice 16):
// agg = adj @ mu (MFMA hi/lo) with inline pos/neg; agg hi/lo -> LDS; @W2; epilogue.
// 512 blocks = 32 b x 16 j-tiles(32).
__global__ __launch_bounds__(512) void k_fused(
    const float* __restrict__ adjF, const float* __restrict__ weight,
    const u16* __restrict__ muthi, const u16* __restrict__ mutlo,
    const u16* __restrict__ w2t, const float* __restrict__ x,
    const float* __restrict__ W1, const float* __restrict__ uvb,
    float* __restrict__ out) {
    __shared__ __align__(16) u16 pool[24576];  // 48 KB
    // phase1 carve: adjL [32][72] @0; mhiL [128][72] @2304; mloL @11520
    u16* adjL = pool;
    u16* mhiL = pool + 2304;
    u16* mloL = pool + 11520;
    // phase2 carve (aliases, barrier-separated): w2L [128][128 swz] @0;
    // ahiL [32][128 swz] @16384; aloL @20480
    u16* w2L = pool;
    u16* ahiL = pool + 16384;
    u16* aloL = pool + 20480;
    __shared__ float psP[16][33], ngP[16][33];  // padded: no bank conflicts
    __shared__ float psF[32], ngF[32];

    int bid = blockIdx.x;
    int vbid = ((bid & 7) << 6) | (bid >> 3);  // XCD chunking (bijective)
    int b = vbid >> 4;
    int j0 = (vbid & 15) * 32;
    int tx = threadIdx.x, lane = tx & 63, w = tx >> 6;

    const float* adjrow = adjF + ((size_t)b * NN + j0) * NN;  // [j][i] rows
    const float* adjcol = adjF + (size_t)b * NN * NN + j0;     // [i][j] cols
    const float* wcol = weight + (size_t)b * NN * NN + j0;     // [i][j] cols
    const u16* mhG = muthi + (size_t)b * PP * NN;
    const u16* mlG = mutlo + (size_t)b * PP * NN;

    // pos/neg mapping: jw = tx&31, kgrp = tx>>5 (16 groups x 4 i's per step)
    int jw = tx & 31, kgrp = tx >> 5;
    float ps = 0.f, ng = 0.f;

    f32x4 acc[2];  // [jt]; wave w owns p-slice [16w, 16w+16)
    acc[0] = (f32x4){0.f, 0.f, 0.f, 0.f};
    acc[1] = (f32x4){0.f, 0.f, 0.f, 0.f};

    for (int step = 0; step < 8; ++step) {
        int k0 = step * 64;
        {  // stage adj tile 32x64 from f32, inline 0/1 -> bf16 (1 float4/thread)
            int jj = tx >> 4, kk0 = (tx & 15) * 4;
            float4 f0 = *(const float4*)(adjrow + (size_t)jj * NN + k0 + kk0);
            uint2 o;
            o.x = (f0.x != 0.f ? 0x3F80u : 0u) | (f0.y != 0.f ? 0x3F800000u : 0u);
            o.y = (f0.z != 0.f ? 0x3F80u : 0u) | (f0.w != 0.f ? 0x3F800000u : 0u);
            *(uint2*)&adjL[jj * 72 + kk0] = o;
        }
        {  // stage muT hi/lo tiles 128x64 (2 uint4 per array per thread)
            int p = tx >> 2, kk0 = (tx & 3) * 16;
            const uint4* sh = (const uint4*)(mhG + (size_t)p * NN + k0 + kk0);
            const uint4* sl = (const uint4*)(mlG + (size_t)p * NN + k0 + kk0);
            uint4 h0 = sh[0], h1 = sh[1], l0 = sl[0], l1 = sl[1];
            *(uint4*)&mhiL[p * 72 + kk0] = h0;
            *(uint4*)&mhiL[p * 72 + kk0 + 8] = h1;
            *(uint4*)&mloL[p * 72 + kk0] = l0;
            *(uint4*)&mloL[p * 72 + kk0 + 8] = l1;
        }
        {  // inline pos/neg: weight+adj column slices (coalesced 128B segments)
#pragma unroll
            for (int kk = 0; kk < 4; ++kk) {
                size_t off = (size_t)(k0 + kgrp * 4 + kk) * NN + jw;
                float wv = wcol[off];
                float av = adjcol[off];  // exactly 0.0 or 1.0
                ps += fmaxf(wv, 0.f) * av;
                ng += fmaxf(-wv, 0.f) * av;
            }
        }
        __syncthreads();
#pragma unroll
        for (int ks = 0; ks < 2; ++ks) {
            int kb = ks * 32 + (lane >> 4) * 8;
            short8v afr[2];
#pragma unroll
            for (int jt = 0; jt < 2; ++jt)
                afr[jt] = *(const short8v*)&adjL[(jt * 16 + (lane & 15)) * 72 + kb];
            int prow = w * 16 + (lane & 15);
            short8v bh = *(const short8v*)&mhiL[prow * 72 + kb];
            short8v bl = *(const short8v*)&mloL[prow * 72 + kb];
#pragma unroll
            for (int jt = 0; jt < 2; ++jt) {
                acc[jt] = __builtin_amdgcn_mfma_f32_16x16x32_bf16(afr[jt], bh, acc[jt], 0, 0, 0);
                acc[jt] = __builtin_amdgcn_mfma_f32_16x16x32_bf16(afr[jt], bl, acc[jt], 0, 0, 0);
            }
        }
        __syncthreads();
    }

    // pos/neg partials -> LDS; acc -> agg hi/lo (XOR-swz); stage W2T (same swz)
    psP[kgrp][jw] = ps;
    ngP[kgrp][jw] = ng;
    {
#pragma unroll
        for (int jt = 0; jt < 2; ++jt)
#pragma unroll
            for (int r = 0; r < 4; ++r) {
                int j = jt * 16 + (lane >> 4) * 4 + r;
                int q = w * 16 + (lane & 15);
                float v = acc[jt][r];
                u32 h = bf16rne(v);
                float lf = v - __uint_as_float(h << 16);
                int qs = q ^ ((j & 7) << 3);
                ahiL[j * 128 + qs] = (u16)h;
                aloL[j * 128 + qs] = (u16)bf16rne(lf);
            }
        int p = tx >> 2, c4 = tx & 3;
#pragma unroll
        for (int c = 0; c < 4; ++c) {
            int cc = c4 * 4 + c;
            int q8 = (cc * 8) ^ ((p & 7) << 3);
            *(uint4*)&w2L[p * 128 + q8] = *(const uint4*)(w2t + p * PP + cc * 8);
        }
    }
    __syncthreads();

    // final pos/neg reduce (32 threads)
    if (tx < 32) {
        float P = 0.f, Ng = 0.f;
#pragma unroll
        for (int g = 0; g < 16; ++g) {
            P += psP[g][tx];
            Ng += ngP[g][tx];
        }
        psF[tx] = P;
        ngF[tx] = Ng;
    }

    // phase 2: D2[j][p'] = sum_q agg[j][q] * W2[q][p']; wave w: p'-slice 16
    f32x4 acc2[2];
    acc2[0] = (f32x4){0.f, 0.f, 0.f, 0.f};
    acc2[1] = (f32x4){0.f, 0.f, 0.f, 0.f};
#pragma unroll
    for (int ks = 0; ks < 4; ++ks) {
        int kb = ks * 32 + (lane >> 4) * 8;
        int prow = w * 16 + (lane & 15);
        short8v bfr = *(const short8v*)&w2L[prow * 128 + (kb ^ ((prow & 7) << 3))];
#pragma unroll
        for (int jt = 0; jt < 2; ++jt) {
            int jrow = jt * 16 + (lane & 15);
            short8v ah = *(const short8v*)&ahiL[jrow * 128 + (kb ^ ((jrow & 7) << 3))];
            short8v al = *(const short8v*)&aloL[jrow * 128 + (kb ^ ((jrow & 7) << 3))];
            acc2[jt] = __builtin_amdgcn_mfma_f32_16x16x32_bf16(ah, bfr, acc2[jt], 0, 0, 0);
            acc2[jt] = __builtin_amdgcn_mfma_f32_16x16x32_bf16(al, bfr, acc2[jt], 0, 0, 0);
        }
    }
    __syncthreads();  // psF/ngF visible to all

    // epilogue: wave w owns p' in [16w, 16w+16)
    int pp = w * 16 + (lane & 15);
    float u_ = uvb[pp];
    float v_ = uvb[PP + pp];
    float bb_ = uvb[2 * PP + pp];
    float w1_ = W1[pp];
    int row0 = b * NN + j0;
#pragma unroll
    for (int jt = 0; jt < 2; ++jt)
#pragma unroll
        for (int r = 0; r < 4; ++r) {
            int jloc = jt * 16 + (lane >> 4) * 4 + r;
            int row = row0 + jloc;
            float xs = x[row];
            float o = acc2[jt][r] + xs * w1_ + psF[jloc] * u_ + ngF[jloc] * v_ + bb_;
            out[(size_t)row * PP + pp] = fmaxf(o, 0.f);
        }
}

extern "C" void kernel_launch(void* const* d_in, const int* in_sizes, int n_in,
                              void* d_out, int out_size, void* d_ws, size_t ws_size,
                              hipStream_t stream) {
    const float* x      = (const float*)d_in[0];
    const float* mu     = (const float*)d_in[1];
    const float* weight = (const float*)d_in[2];
    const float* adj    = (const float*)d_in[3];
    const float* W1     = (const float*)d_in[4];
    const float* b1     = (const float*)d_in[5];
    const float* W2     = (const float*)d_in[6];
    const float* b2     = (const float*)d_in[7];
    const float* W3     = (const float*)d_in[8];
    const float* b3     = (const float*)d_in[9];
    const float* theta4 = (const float*)d_in[10];
    float* out = (float*)d_out;

    float* ws  = (float*)d_ws;
    float* uvb = ws + UVB_OFF;
    u16* muthi = (u16*)((char*)d_ws + MUTHI_OFF);
    u16* mutlo = (u16*)((char*)d_ws + MUTLO_OFF);
    u16* w2t   = (u16*)((char*)d_ws + W2T_OFF);

    k_aux<<<258, 256, 0, stream>>>(mu, W2, theta4, W3, b1, b2, b3, uvb,
                                   muthi, mutlo, w2t);

    k_fused<<<512, 512, 0, stream>>>(adj, weight, muthi, mutlo, w2t, x, W1,
                                     uvb, out);
}